// Round 6
// baseline (103.933 us; speedup 1.0000x reference)
//
#include <hip/hip_runtime.h>

#define M_BASIS 100
constexpr float INV_TWO_PI = 0.15915494309189535f;

// Kernel A: one thread per row. Compute Sigma (sym of P^-1 with P=-2Q),
// Mu = Sigma@eta, store {S00,S01,S11,Mu0,Mu1,2*S01} stride-8 in d_ws.
__global__ __launch_bounds__(256) void row_kernel(
    const float* __restrict__ theta, float* __restrict__ rp, int N)
{
    int n = blockIdx.x * 256 + threadIdx.x;
    if (n >= N) return;
    const float* th = theta + n * 6;
    float2 e  = *(const float2*)(th);
    float2 qa = *(const float2*)(th + 2);
    float2 qb = *(const float2*)(th + 4);

    float detQ = qa.x * qb.y - qa.y * qb.x;
    float r    = __builtin_amdgcn_rcpf(detQ);
    float h    = -0.5f * r;
    float S00  = qb.y * h;
    float S11  = qa.x * h;
    float S01  = (qa.y + qb.x) * (-0.5f * h);
    float Mu0  = S00 * e.x + S01 * e.y;
    float Mu1  = S01 * e.x + S11 * e.y;

    float4* o = (float4*)(rp + 8 * (size_t)n);
    o[0] = make_float4(S00, S01, S11, Mu0);
    o[1] = make_float4(Mu1, 2.0f * S01, 0.0f, 0.0f);
}

// Kernel B: one thread per output element. Basis in LDS as SoA (stride-1
// lane access -> conflict-free). Row params via two broadcast float4 loads.
__global__ __launch_bounds__(256) void cs_kernel(
    const float* __restrict__ rp,
    const float* __restrict__ basis_mu,
    const float* __restrict__ basis_sigma,
    float* __restrict__ out,
    int total)
{
    __shared__ float B00[M_BASIS], B11[M_BASIS], Bs[M_BASIS], Bp[M_BASIS];
    __shared__ float M0[M_BASIS], M1[M_BASIS];

    int t = threadIdx.x;
    if (t < M_BASIS) {
        float4 s = ((const float4*)basis_sigma)[t];
        float2 m = ((const float2*)basis_mu)[t];
        B00[t] = s.x; B11[t] = s.w;
        Bs[t]  = s.y + s.z;          // b01 + b10
        Bp[t]  = s.y * s.z;          // b01 * b10
        M0[t]  = m.x; M1[t]  = m.y;
    }
    __syncthreads();

    int i = blockIdx.x * 256 + t;
    if (i >= total) return;
    unsigned n = (unsigned)i / 100u;          // compiler magic-mul
    unsigned j = (unsigned)i - n * 100u;

    const float4* r4 = (const float4*)(rp + 8 * (size_t)n);
    float4 ra = r4[0];
    float4 rb = r4[1];
    float S00 = ra.x, S01 = ra.y, S11 = ra.z, Mu0 = ra.w;
    float Mu1 = rb.x, twoS01 = rb.y;

    // detC = c00*c11 - (S01^2 + S01*Bs + Bp)
    float c00 = S00 + B00[j];
    float c11 = S11 + B11[j];
    float tq  = fmaf(S01, Bs[j], fmaf(S01, S01, Bp[j]));
    float detC = fmaf(c00, c11, -tq);

    float d0 = Mu0 - M0[j];
    float d1 = Mu1 - M1[j];
    float cs = twoS01 + Bs[j];                // c01 + c10
    float num = d0 * d0 * c11;
    num = fmaf(d1 * d1, c00, num);
    num = fmaf(-(d0 * d1), cs, num);

    float rs = __builtin_amdgcn_rsqf(detC);
    float ex = __expf(-0.5f * num * (rs * rs));
    out[i] = ex * (INV_TWO_PI * rs);
}

extern "C" void kernel_launch(void* const* d_in, const int* in_sizes, int n_in,
                              void* d_out, int out_size, void* d_ws, size_t ws_size,
                              hipStream_t stream) {
    const float* theta      = (const float*)d_in[0];   // [N,6]
    const float* basis_mu   = (const float*)d_in[1];   // [M,2]
    const float* basis_sig  = (const float*)d_in[2];   // [M,2,2]
    float* out = (float*)d_out;                        // [N,M]
    float* rp  = (float*)d_ws;                         // [N,8] row params

    int N = in_sizes[0] / 6;
    int total = out_size;                              // N * M

    int gridA = (N + 255) / 256;
    hipLaunchKernelGGL(row_kernel, dim3(gridA), dim3(256), 0, stream,
                       theta, rp, N);

    int gridB = (total + 255) / 256;
    hipLaunchKernelGGL(cs_kernel, dim3(gridB), dim3(256), 0, stream,
                       rp, basis_mu, basis_sig, out, total);
}

// Round 8
// 87.435 us; speedup vs baseline: 1.1887x; 1.1887x over previous
//
#include <hip/hip_runtime.h>

#define M_BASIS 100
constexpr float INV_TWO_PI = 0.15915494309189535f;

typedef float vf4 __attribute__((ext_vector_type(4)));

// Persistent kernel: 2048 blocks x 256 = 8192 waves (32 waves/CU), grid-stride
// over row PAIRS. Lanes 0-24 own row 2p (j = 4*lane..4*lane+3), lanes 25-49 own
// row 2p+1 (j = 4*(lane-25)..). Each lane loads its own row's theta and computes
// row params per-lane (no divergence). One float4 nontemporal store per lane
// covers the whole 800B pair contiguously (50 dwordx4 lanes).
__global__ __launch_bounds__(256) void cs_kernel(
    const float* __restrict__ theta,
    const float* __restrict__ basis_mu,
    const float* __restrict__ basis_sigma,
    float* __restrict__ out,
    int N)
{
    const int lane = threadIdx.x & 63;
    const int waves_per_block = blockDim.x >> 6;
    const int wave_id = blockIdx.x * waves_per_block + (threadIdx.x >> 6);
    const int num_waves = gridDim.x * waves_per_block;

    const bool active = (lane < 50);
    const int sub = (lane < 25) ? lane : lane - 25;   // j-group 0..24
    const int rsel = (lane < 25) ? 0 : 1;             // which row of the pair

    // Basis registers for j = 4*sub + k, k=0..3
    float B00[4], B11[4], Bs[4], Bp[4], Mx[4], My[4];
    #pragma unroll
    for (int k = 0; k < 4; ++k) {
        int j = active ? (4 * sub + k) : 0;
        float4 s = ((const float4*)basis_sigma)[j];
        float2 m = ((const float2*)basis_mu)[j];
        B00[k] = s.x; B11[k] = s.w;
        Bs[k]  = s.y + s.z;
        Bp[k]  = s.y * s.z;
        Mx[k]  = m.x; My[k]  = m.y;
    }

    const int pairs = N >> 1;   // N even (131072)

    #pragma unroll 2
    for (int p = wave_id; p < pairs; p += num_waves) {
        const int n = 2 * p + rsel;
        const float* th = theta + n * 6;
        float2 e  = *(const float2*)(th);       // eta
        float2 qa = *(const float2*)(th + 2);   // q00 q01
        float2 qb = *(const float2*)(th + 4);   // q10 q11

        // Sigma = -0.5 * sym(Q^-1); Mu = Sigma @ eta   (per-lane, own row)
        float detQ = qa.x * qb.y - qa.y * qb.x;
        float r    = __builtin_amdgcn_rcpf(detQ);
        float h    = -0.5f * r;
        float S00  = qb.y * h;
        float S11  = qa.x * h;
        float S01  = (qa.y + qb.x) * (-0.5f * h);
        float Mu0  = S00 * e.x + S01 * e.y;
        float Mu1  = S01 * e.x + S11 * e.y;
        float twoS01 = S01 + S01;

        if (active) {
            vf4 res;
            #pragma unroll
            for (int k = 0; k < 4; ++k) {
                float c00 = S00 + B00[k];
                float c11 = S11 + B11[k];
                float tq  = fmaf(S01, Bs[k], fmaf(S01, S01, Bp[k]));
                float detC = fmaf(c00, c11, -tq);
                float d0 = Mu0 - Mx[k];
                float d1 = Mu1 - My[k];
                float cs = twoS01 + Bs[k];           // c01 + c10
                float num = d0 * d0 * c11;
                num = fmaf(d1 * d1, c00, num);
                num = fmaf(-(d0 * d1), cs, num);
                float rs = __builtin_amdgcn_rsqf(detC);
                res[k] = __expf(-0.5f * num * (rs * rs)) * (INV_TWO_PI * rs);
            }
            // pair base: 200 floats = 50 float4; lane l stores float4 #l
            vf4* obase = (vf4*)(out + (size_t)p * 2 * M_BASIS);
            __builtin_nontemporal_store(res, obase + lane);
        }
    }
}

extern "C" void kernel_launch(void* const* d_in, const int* in_sizes, int n_in,
                              void* d_out, int out_size, void* d_ws, size_t ws_size,
                              hipStream_t stream) {
    const float* theta      = (const float*)d_in[0];   // [N,6]
    const float* basis_mu   = (const float*)d_in[1];   // [M,2]
    const float* basis_sig  = (const float*)d_in[2];   // [M,2,2]
    float* out = (float*)d_out;                        // [N,M]

    int N = in_sizes[0] / 6;
    int block = 256;   // 4 waves/block
    int grid = 2048;   // 8192 waves = 32 waves/CU persistent
    hipLaunchKernelGGL(cs_kernel, dim3(grid), dim3(block), 0, stream,
                       theta, basis_mu, basis_sig, out, N);
}